// Round 15
// baseline (337.704 us; speedup 1.0000x reference)
//
#include <hip/hip_runtime.h>
#include <hip/hip_bf16.h>
#include <cstdint>
#include <cstddef>

// RBF Gram matrix: K[i,j] = exp(-gamma * ||a_i - b_j||^2), A,B: [8192,256] f32.
// Out: [8192,8192] f32.
//
// ROUND-15 DECOMPOSITION PROBE. Six structural levers (R8-R14) each predicted
// +15-30% and measured +-2%; the GEMM never surfaces in top-5 counters. This
// round splits the kernel into its two suspect halves, each repeated 4x so it
// exceeds the ~155us fill dispatches and becomes counter-visible:
//   probe_stores<4>:  exact R13 store pattern + exp2, acc=0 (junk, later
//                     overwritten) -> store-path ceiling for this pattern.
//   probe_compute<4>: exact R13 pipeline, stores -> asm reg sinks (no DCE)
//                     -> pure compute/staging chain + real OccupancyPercent.
// Real R13 kernel runs LAST -> final output correct.

#define GAMMA_F 0.00390625f
#define LOG2E_F 1.44269504088896340736f

typedef __attribute__((ext_vector_type(8))) short short8;   // 8 bf16
typedef __attribute__((ext_vector_type(4))) float f32x4;    // acc / 16B

constexpr int KD = 256;
constexpr int ND = 8192;
constexpr int NKT = KD / 32;   // 8 K-steps of BK=32

__device__ __forceinline__ unsigned short f2b(float f) {
  unsigned int u = __float_as_uint(f);
  u += 0x7FFFu + ((u >> 16) & 1u);
  return (unsigned short)(u >> 16);
}

// Raw v_exp_f32: exact for our arg range [-8, 0].
__device__ __forceinline__ float fast_exp2(float x) {
#if __has_builtin(__builtin_amdgcn_exp2f)
  return __builtin_amdgcn_exp2f(x);
#else
  float r;
  asm volatile("v_exp_f32 %0, %1\n\ts_nop 1" : "=v"(r) : "v"(x));
  return r;
#endif
}

__device__ __forceinline__ void gload_lds16(const void* g, void* l) {
  __builtin_amdgcn_global_load_lds(
      (const __attribute__((address_space(1))) unsigned int*)g,
      (__attribute__((address_space(3))) unsigned int*)l, 16, 0, 0);
}

#define FULL_BARRIER() do { asm volatile("" ::: "memory"); \
  __builtin_amdgcn_s_barrier(); asm volatile("" ::: "memory"); } while (0)

// ---------------------------------------------------------------------------
// Prepass: pre-scaled row norms n = -gamma*log2e*||row||^2 + bf16 convert.
// ---------------------------------------------------------------------------
__global__ __launch_bounds__(256) void norm_convert_kernel(
    const float* __restrict__ A, const float* __restrict__ B,
    unsigned short* Abf, unsigned short* Bbf,
    float* __restrict__ na, float* __restrict__ nb)
{
  const int lane = threadIdx.x & 63;
  const int row = blockIdx.x * 4 + (threadIdx.x >> 6);
  const float* src = A;
  unsigned short* dst = Abf;
  float* nrm = na;
  int r = row;
  if (row >= ND) { src = B; dst = Bbf; nrm = nb; r = row - ND; }

  const float4 v = *(const float4*)(src + (size_t)r * KD + lane * 4);
  float s = v.x * v.x + v.y * v.y + v.z * v.z + v.w * v.w;
  #pragma unroll
  for (int off = 32; off >= 1; off >>= 1) s += __shfl_xor(s, off, 64);

  if (dst) {
    const unsigned int p0 = (unsigned)f2b(v.x) | ((unsigned)f2b(v.y) << 16);
    const unsigned int p1 = (unsigned)f2b(v.z) | ((unsigned)f2b(v.w) << 16);
    *(uint2*)(dst + (size_t)r * KD + lane * 4) = make_uint2(p0, p1);
  }
  if (lane == 0) nrm[r] = -GAMMA_F * LOG2E_F * s;
}

// ---------------------------------------------------------------------------
// Shared tile-mapping helper (R13 geometry).
// ---------------------------------------------------------------------------
struct TileMap {
  int brow, bcol, wm, wn, lane;
};
__device__ __forceinline__ TileMap tile_map(int bid, int t) {
  TileMap m;
  m.lane = t & 63;
  const int wid = t >> 6;
  m.wm = wid >> 1; m.wn = wid & 1;
  const int x = bid & 7;
  const int k = bid >> 3;
  m.brow = (((x >> 1) << 4) + (k >> 5)) << 7;
  m.bcol = (((x & 1) << 5) + (k & 31)) << 7;
  return m;
}

// ---------------------------------------------------------------------------
// PROBE 1: exact R13 store pattern + exp2 math, acc = 0. Repeated NREP times
// (identical deterministic writes; real kernel runs afterwards and overwrites
// with correct values).
// ---------------------------------------------------------------------------
template <int NREP>
__global__ __launch_bounds__(256) void probe_stores_kernel(
    const float* __restrict__ na, const float* __restrict__ nb,
    float* __restrict__ C)
{
  const TileMap m = tile_map(blockIdx.x, threadIdx.x);
  f32x4 b4s[4];
  #pragma unroll
  for (int fn = 0; fn < 4; ++fn) {
    const int j0 = m.bcol + m.wn * 64 + fn * 16 + ((m.lane >> 4) << 2);
    b4s[fn] = *(const f32x4*)&nb[j0];
  }
  for (int rep = 0; rep < NREP; ++rep) {
    #pragma unroll
    for (int fm = 0; fm < 4; ++fm) {
      const int i = m.brow + m.wm * 64 + fm * 16 + (m.lane & 15);
      const float an = na[i];
      float* crow = C + (size_t)i * ND;
      #pragma unroll
      for (int fn = 0; fn < 4; ++fn) {
        const int j0 = m.bcol + m.wn * 64 + fn * 16 + ((m.lane >> 4) << 2);
        f32x4 arg = b4s[fn] + an;
        f32x4 o;
        o[0] = fast_exp2(arg[0]);
        o[1] = fast_exp2(arg[1]);
        o[2] = fast_exp2(arg[2]);
        o[3] = fast_exp2(arg[3]);
        *(f32x4*)&crow[j0] = o;
      }
    }
    asm volatile("" ::: "memory");   // keep per-rep stores (not dead)
  }
}

// ---------------------------------------------------------------------------
// PROBE 2: exact R13 pipeline, stores replaced by register sinks. NREP reps.
// ---------------------------------------------------------------------------
template <int NREP>
__global__ __launch_bounds__(256, 3) void probe_compute_kernel(
    const unsigned short* __restrict__ Abf, const unsigned short* __restrict__ Bbf,
    const float* __restrict__ na, const float* __restrict__ nb,
    float* __restrict__ C)
{
  __shared__ __align__(16) char smem[49152];
  const int t = threadIdx.x;
  const TileMap m = tile_map(blockIdx.x, t);
  const int wid = t >> 6;

  const int srow = t >> 2;
  const int scolb = (((t & 3) ^ ((t >> 3) & 3)) << 4);

  int aoff[4], boff[4];
  #pragma unroll
  for (int f = 0; f < 4; ++f) {
    const int ra = m.wm * 64 + f * 16 + (m.lane & 15);
    aoff[f] = ra * 64 + (((m.lane >> 4) * 16) ^ (((ra >> 1) & 3) << 4));
    const int rb = m.wn * 64 + f * 16 + (m.lane & 15);
    boff[f] = 8192 + rb * 64 + (((m.lane >> 4) * 16) ^ (((rb >> 1) & 3) << 4));
  }

  const char* Ab = (const char*)Abf;
  const char* Bb = (const char*)Bbf;

  auto stage = [&](int buf, int kt) {
    #pragma unroll
    for (int h = 0; h < 2; ++h) {
      gload_lds16(Ab + (size_t)(m.brow + h * 64 + srow) * 512 + kt * 64 + scolb,
                  smem + buf * 16384 + h * 4096 + (wid << 10));
      gload_lds16(Bb + (size_t)(m.bcol + h * 64 + srow) * 512 + kt * 64 + scolb,
                  smem + buf * 16384 + 8192 + h * 4096 + (wid << 10));
    }
  };

  for (int rep = 0; rep < NREP; ++rep) {
    f32x4 acc[4][4] = {};

    stage(0, 0);
    stage(1, 1);
    asm volatile("s_waitcnt vmcnt(4)" ::: "memory");
    FULL_BARRIER();

    #pragma unroll
    for (int kt = 0; kt < NKT; ++kt) {
      const int cb = (kt % 3) * 16384;
      short8 af[4], bfv[4];
      #pragma unroll
      for (int f = 0; f < 4; ++f) {
        af[f]  = *(const short8*)(smem + cb + aoff[f]);
        bfv[f] = *(const short8*)(smem + cb + boff[f]);
      }
      if (kt + 2 < NKT) stage((kt + 2) % 3, kt + 2);

      __builtin_amdgcn_s_setprio(1);
      #pragma unroll
      for (int fm = 0; fm < 4; ++fm)
        #pragma unroll
        for (int fn = 0; fn < 4; ++fn)
          acc[fm][fn] = __builtin_amdgcn_mfma_f32_16x16x32_bf16(
              bfv[fn], af[fm], acc[fm][fn], 0, 0, 0);
      __builtin_amdgcn_s_setprio(0);

      if (kt < NKT - 1) {
        if (kt + 2 < NKT) { asm volatile("s_waitcnt vmcnt(4)" ::: "memory"); }
        else              { asm volatile("s_waitcnt vmcnt(0)" ::: "memory"); }
        FULL_BARRIER();
      }
    }

    // Epilogue math, result sunk into registers (no stores, no DCE).
    const float c2 = 2.0f * GAMMA_F * LOG2E_F;
    f32x4 b4s[4];
    #pragma unroll
    for (int fn = 0; fn < 4; ++fn) {
      const int j0 = m.bcol + m.wn * 64 + fn * 16 + ((m.lane >> 4) << 2);
      b4s[fn] = *(const f32x4*)&nb[j0];
    }
    #pragma unroll
    for (int fm = 0; fm < 4; ++fm) {
      const int i = m.brow + m.wm * 64 + fm * 16 + (m.lane & 15);
      const float an = na[i];
      #pragma unroll
      for (int fn = 0; fn < 4; ++fn) {
        f32x4 arg = b4s[fn] + an;
        arg = acc[fm][fn] * c2 + arg;
        f32x4 o;
        o[0] = fast_exp2(arg[0]);
        o[1] = fast_exp2(arg[1]);
        o[2] = fast_exp2(arg[2]);
        o[3] = fast_exp2(arg[3]);
        asm volatile("" :: "v"(o[0]), "v"(o[1]), "v"(o[2]), "v"(o[3]));
      }
    }

    // Rep boundary: drain everything so buf0 restage is safe.
    asm volatile("s_waitcnt vmcnt(0) lgkmcnt(0)" ::: "memory");
    FULL_BARRIER();
  }
}

// ---------------------------------------------------------------------------
// REAL kernel: exact R13 (best, 84.0us). Runs last -> correct output.
// ---------------------------------------------------------------------------
__global__ __launch_bounds__(256, 3) void rbf_gemm_kernel(
    const unsigned short* __restrict__ Abf, const unsigned short* __restrict__ Bbf,
    const float* __restrict__ na, const float* __restrict__ nb,
    float* __restrict__ C)
{
  __shared__ __align__(16) char smem[49152];
  const int t = threadIdx.x;
  const TileMap m = tile_map(blockIdx.x, t);
  const int wid = t >> 6;

  const int srow = t >> 2;
  const int scolb = (((t & 3) ^ ((t >> 3) & 3)) << 4);

  int aoff[4], boff[4];
  #pragma unroll
  for (int f = 0; f < 4; ++f) {
    const int ra = m.wm * 64 + f * 16 + (m.lane & 15);
    aoff[f] = ra * 64 + (((m.lane >> 4) * 16) ^ (((ra >> 1) & 3) << 4));
    const int rb = m.wn * 64 + f * 16 + (m.lane & 15);
    boff[f] = 8192 + rb * 64 + (((m.lane >> 4) * 16) ^ (((rb >> 1) & 3) << 4));
  }

  const char* Ab = (const char*)Abf;
  const char* Bb = (const char*)Bbf;

  auto stage = [&](int buf, int kt) {
    #pragma unroll
    for (int h = 0; h < 2; ++h) {
      gload_lds16(Ab + (size_t)(m.brow + h * 64 + srow) * 512 + kt * 64 + scolb,
                  smem + buf * 16384 + h * 4096 + (wid << 10));
      gload_lds16(Bb + (size_t)(m.bcol + h * 64 + srow) * 512 + kt * 64 + scolb,
                  smem + buf * 16384 + 8192 + h * 4096 + (wid << 10));
    }
  };

  f32x4 acc[4][4] = {};

  stage(0, 0);
  stage(1, 1);
  asm volatile("s_waitcnt vmcnt(4)" ::: "memory");
  FULL_BARRIER();

  #pragma unroll
  for (int kt = 0; kt < NKT; ++kt) {
    const int cb = (kt % 3) * 16384;

    short8 af[4], bfv[4];
    #pragma unroll
    for (int f = 0; f < 4; ++f) {
      af[f]  = *(const short8*)(smem + cb + aoff[f]);
      bfv[f] = *(const short8*)(smem + cb + boff[f]);
    }
    if (kt + 2 < NKT) stage((kt + 2) % 3, kt + 2);

    __builtin_amdgcn_s_setprio(1);
    #pragma unroll
    for (int fm = 0; fm < 4; ++fm)
      #pragma unroll
      for (int fn = 0; fn < 4; ++fn)
        acc[fm][fn] = __builtin_amdgcn_mfma_f32_16x16x32_bf16(
            bfv[fn], af[fm], acc[fm][fn], 0, 0, 0);
    __builtin_amdgcn_s_setprio(0);

    if (kt < NKT - 1) {
      if (kt + 2 < NKT) { asm volatile("s_waitcnt vmcnt(4)" ::: "memory"); }
      else              { asm volatile("s_waitcnt vmcnt(0)" ::: "memory"); }
      FULL_BARRIER();
    }
  }

  const float c2 = 2.0f * GAMMA_F * LOG2E_F;
  f32x4 b4s[4];
  #pragma unroll
  for (int fn = 0; fn < 4; ++fn) {
    const int j0 = m.bcol + m.wn * 64 + fn * 16 + ((m.lane >> 4) << 2);
    b4s[fn] = *(const f32x4*)&nb[j0];
  }
  #pragma unroll
  for (int fm = 0; fm < 4; ++fm) {
    const int i = m.brow + m.wm * 64 + fm * 16 + (m.lane & 15);
    const float an = na[i];
    float* crow = C + (size_t)i * ND;
    #pragma unroll
    for (int fn = 0; fn < 4; ++fn) {
      const int j0 = m.bcol + m.wn * 64 + fn * 16 + ((m.lane >> 4) << 2);
      f32x4 arg = b4s[fn] + an;
      arg = acc[fm][fn] * c2 + arg;
      f32x4 o;
      o[0] = fast_exp2(arg[0]);
      o[1] = fast_exp2(arg[1]);
      o[2] = fast_exp2(arg[2]);
      o[3] = fast_exp2(arg[3]);
      *(f32x4*)&crow[j0] = o;
    }
  }
}

// ---------------------------------------------------------------------------
// Fallback (tiny d_ws): 128x128 serial kernel, f32->bf16 inline (no probes).
// ---------------------------------------------------------------------------
__global__ __launch_bounds__(256) void rbf_gemm_fallback(
    const float* __restrict__ Af, const float* __restrict__ Bf,
    const float* __restrict__ na, const float* __restrict__ nb,
    float* __restrict__ C)
{
  __shared__ __align__(16) char smem[16384];
  const int t = threadIdx.x;
  const int lane = t & 63;
  const int wid = t >> 6;
  const int wm = wid >> 1, wn = wid & 1;
  const int bid = blockIdx.x;
  const int brow = (bid >> 6) << 7;
  const int bcol = (bid & 63) << 7;
  const int srow = t >> 2;
  const int scolb = (((t & 3) ^ ((t >> 3) & 3)) << 4);

  int aoff[4], boff[4];
  #pragma unroll
  for (int f = 0; f < 4; ++f) {
    const int ra = wm * 64 + f * 16 + (lane & 15);
    aoff[f] = ra * 64 + (((lane >> 4) * 16) ^ (((ra >> 1) & 3) << 4));
    const int rb = wn * 64 + f * 16 + (lane & 15);
    boff[f] = 8192 + rb * 64 + (((lane >> 4) * 16) ^ (((rb >> 1) & 3) << 4));
  }

  f32x4 acc[4][4] = {};
  for (int kt = 0; kt < 8; ++kt) {
    #pragma unroll
    for (int h = 0; h < 2; ++h) {
      const float* sa = Af + (size_t)(brow + h * 64 + srow) * KD + kt * 32 + (scolb >> 1);
      const float4 a0 = *(const float4*)sa;
      const float4 a1 = *(const float4*)(sa + 4);
      *(uint4*)(smem + h * 4096 + t * 16) = make_uint4(
          (unsigned)f2b(a0.x) | ((unsigned)f2b(a0.y) << 16),
          (unsigned)f2b(a0.z) | ((unsigned)f2b(a0.w) << 16),
          (unsigned)f2b(a1.x) | ((unsigned)f2b(a1.y) << 16),
          (unsigned)f2b(a1.z) | ((unsigned)f2b(a1.w) << 16));
      const float* sb = Bf + (size_t)(bcol + h * 64 + srow) * KD + kt * 32 + (scolb >> 1);
      const float4 b0 = *(const float4*)sb;
      const float4 b1 = *(const float4*)(sb + 4);
      *(uint4*)(smem + 8192 + h * 4096 + t * 16) = make_uint4(
          (unsigned)f2b(b0.x) | ((unsigned)f2b(b0.y) << 16),
          (unsigned)f2b(b0.z) | ((unsigned)f2b(b0.w) << 16),
          (unsigned)f2b(b1.x) | ((unsigned)f2b(b1.y) << 16),
          (unsigned)f2b(b1.z) | ((unsigned)f2b(b1.w) << 16));
    }
    __syncthreads();
    short8 af[4], bfv[4];
    #pragma unroll
    for (int f = 0; f < 4; ++f) {
      af[f]  = *(const short8*)(smem + aoff[f]);
      bfv[f] = *(const short8*)(smem + boff[f]);
    }
    #pragma unroll
    for (int fm = 0; fm < 4; ++fm)
      #pragma unroll
      for (int fn = 0; fn < 4; ++fn)
        acc[fm][fn] = __builtin_amdgcn_mfma_f32_16x16x32_bf16(
            bfv[fn], af[fm], acc[fm][fn], 0, 0, 0);
    __syncthreads();
  }

  const float c2 = 2.0f * GAMMA_F * LOG2E_F;
  #pragma unroll
  for (int fm = 0; fm < 4; ++fm) {
    const int i = brow + wm * 64 + fm * 16 + (lane & 15);
    const float an = na[i];
    float* crow = C + (size_t)i * ND;
    #pragma unroll
    for (int fn = 0; fn < 4; ++fn) {
      const int j0 = bcol + wn * 64 + fn * 16 + ((lane >> 4) << 2);
      const f32x4 b4 = *(const f32x4*)&nb[j0];
      f32x4 arg = b4 + an;
      arg = acc[fm][fn] * c2 + arg;
      f32x4 o;
      o[0] = fast_exp2(arg[0]);
      o[1] = fast_exp2(arg[1]);
      o[2] = fast_exp2(arg[2]);
      o[3] = fast_exp2(arg[3]);
      *(f32x4*)&crow[j0] = o;
    }
  }
}

// ---------------------------------------------------------------------------
extern "C" void kernel_launch(void* const* d_in, const int* in_sizes, int n_in,
                              void* d_out, int out_size, void* d_ws, size_t ws_size,
                              hipStream_t stream) {
  const float* A = (const float*)d_in[0];
  const float* B = (const float*)d_in[1];
  float* C = (float*)d_out;

  const size_t bfBytes = (size_t)ND * KD * 2;   // 4 MiB per matrix
  const size_t normBytes = (size_t)ND * 4;
  char* ws = (char*)d_ws;
  const int grid = (ND / 128) * (ND / 128);     // 4096

  if (ws_size >= 2 * bfBytes + 2 * normBytes) {
    unsigned short* Abf = (unsigned short*)ws;
    unsigned short* Bbf = (unsigned short*)(ws + bfBytes);
    float* na = (float*)(ws + 2 * bfBytes);
    float* nb = (float*)(ws + 2 * bfBytes + normBytes);
    hipLaunchKernelGGL(norm_convert_kernel, dim3(2 * ND / 4), dim3(256), 0, stream,
                       A, B, Abf, Bbf, na, nb);
    // PROBE 1: store-path ceiling (junk values; overwritten by real kernel).
    hipLaunchKernelGGL((probe_stores_kernel<4>), dim3(grid), dim3(256), 0, stream,
                       na, nb, C);
    // PROBE 2: compute/staging chain (no stores).
    hipLaunchKernelGGL((probe_compute_kernel<4>), dim3(grid), dim3(256), 0, stream,
                       Abf, Bbf, na, nb, C);
    // REAL kernel (R13): correct output.
    hipLaunchKernelGGL(rbf_gemm_kernel, dim3(grid), dim3(256), 0, stream,
                       Abf, Bbf, na, nb, C);
  } else {
    float* na = (float*)ws;
    float* nb = (float*)(ws + normBytes);
    hipLaunchKernelGGL(norm_convert_kernel, dim3(2 * ND / 4), dim3(256), 0, stream,
                       A, B, (unsigned short*)nullptr, (unsigned short*)nullptr, na, nb);
    hipLaunchKernelGGL(rbf_gemm_fallback, dim3(grid), dim3(256), 0, stream,
                       A, B, na, nb, C);
  }
}

// Round 16
// 84.368 us; speedup vs baseline: 4.0027x; 4.0027x over previous
//
#include <hip/hip_runtime.h>
#include <hip/hip_bf16.h>
#include <cstdint>
#include <cstddef>

// RBF Gram matrix: K[i,j] = exp(-gamma * ||a_i - b_j||^2), A,B: [8192,256] f32.
// Out: [8192,8192] f32.
//
// Round-16: 256x256 tile, 4-phase-per-K-tile interleave (m201 mechanism,
// simplified). R15 probes: compute chain ~half the 84us wall; LDS-read pipe
// (20.5us/CU at 128^2 tile) is the largest reducible term; L3 absorbs the C
// write stream. 256^2 cuts LDS-bytes/FLOP 1.33x and block-slots/CU 16->4.
// 8 waves (2Mx4N), BK=32, 2x32KB LDS buffers, acc[8][4] (128 AGPR). Phases:
// {ds_read 2 A-frags | front-loaded stage (phases 0-1) | 8 MFMA setprio-
// wrapped}; ONE vmcnt(0)+s_barrier per K-tile (stage loads are >=2 phases
// old -> wait nearly free). Verified pieces reused verbatim: involution
// f(b)=b^(((b>>7)&3)<<4) (64B rows, bank conflicts measured 0), swapped-
// operand MFMA C-mapping, lean exp2 epilogue, XCD region map.

#define GAMMA_F 0.00390625f
#define LOG2E_F 1.44269504088896340736f

typedef __attribute__((ext_vector_type(8))) short short8;   // 8 bf16
typedef __attribute__((ext_vector_type(4))) float f32x4;    // acc / 16B

constexpr int KD = 256;
constexpr int ND = 8192;
constexpr int NKT = KD / 32;   // 8 K-tiles of BK=32

__device__ __forceinline__ unsigned short f2b(float f) {
  unsigned int u = __float_as_uint(f);
  u += 0x7FFFu + ((u >> 16) & 1u);
  return (unsigned short)(u >> 16);
}

// Raw v_exp_f32: exact for our arg range [-8, 0].
__device__ __forceinline__ float fast_exp2(float x) {
#if __has_builtin(__builtin_amdgcn_exp2f)
  return __builtin_amdgcn_exp2f(x);
#else
  float r;
  asm volatile("v_exp_f32 %0, %1\n\ts_nop 1" : "=v"(r) : "v"(x));
  return r;
#endif
}

__device__ __forceinline__ void gload_lds16(const void* g, void* l) {
  __builtin_amdgcn_global_load_lds(
      (const __attribute__((address_space(1))) unsigned int*)g,
      (__attribute__((address_space(3))) unsigned int*)l, 16, 0, 0);
}

#define FULL_BARRIER() do { asm volatile("" ::: "memory"); \
  __builtin_amdgcn_s_barrier(); asm volatile("" ::: "memory"); } while (0)

// ---------------------------------------------------------------------------
// Prepass: pre-scaled row norms n = -gamma*log2e*||row||^2 + bf16 convert.
// ---------------------------------------------------------------------------
__global__ __launch_bounds__(256) void norm_convert_kernel(
    const float* __restrict__ A, const float* __restrict__ B,
    unsigned short* Abf, unsigned short* Bbf,
    float* __restrict__ na, float* __restrict__ nb)
{
  const int lane = threadIdx.x & 63;
  const int row = blockIdx.x * 4 + (threadIdx.x >> 6);
  const float* src = A;
  unsigned short* dst = Abf;
  float* nrm = na;
  int r = row;
  if (row >= ND) { src = B; dst = Bbf; nrm = nb; r = row - ND; }

  const float4 v = *(const float4*)(src + (size_t)r * KD + lane * 4);
  float s = v.x * v.x + v.y * v.y + v.z * v.z + v.w * v.w;
  #pragma unroll
  for (int off = 32; off >= 1; off >>= 1) s += __shfl_xor(s, off, 64);

  if (dst) {
    const unsigned int p0 = (unsigned)f2b(v.x) | ((unsigned)f2b(v.y) << 16);
    const unsigned int p1 = (unsigned)f2b(v.z) | ((unsigned)f2b(v.w) << 16);
    *(uint2*)(dst + (size_t)r * KD + lane * 4) = make_uint2(p0, p1);
  }
  if (lane == 0) nrm[r] = -GAMMA_F * LOG2E_F * s;
}

// ---------------------------------------------------------------------------
// Main 256x256 GEMM + RBF epilogue. 512 threads = 8 waves (2M x 4N); wave
// owns 128x64 of C: acc[8][4] 16x16 frags. LDS 64KB: buf b (b in {0,1}):
// A[256][64B] @ b*32768, B[256][64B] @ b*32768+16384.
//
// Per K-tile kt (buf = kt&1): read 4 B-frags once; 4 phases q: {read A-frags
// 2q,2q+1; stage calls for kt+1 front-loaded in q=0,1; 8 MFMA}. Boundary:
// vmcnt(0) (loads >=2 phases old) + s_barrier, then buffer swap.
// ---------------------------------------------------------------------------
__global__ __launch_bounds__(512, 2) void rbf_gemm_kernel(
    const unsigned short* __restrict__ Abf, const unsigned short* __restrict__ Bbf,
    const float* __restrict__ na, const float* __restrict__ nb,
    float* __restrict__ C)
{
  __shared__ __align__(16) char smem[65536];
  const int t = threadIdx.x;
  const int lane = t & 63;
  const int wid = t >> 6;          // 0..7
  const int wm = wid >> 2;         // 0..1 (128-row half)
  const int wn = wid & 3;          // 0..3 (64-col quarter)

  // XCD mapping (bijective, 8 XCDs x 128 on the 32x32 tile grid): XCD x owns
  // an 8-tile-row x 16-tile-col region (B panel 8MB bf16 spread over 2 cols
  // of regions; A panel 4MB -> L2/L3 resident).
  const int bid = blockIdx.x;
  const int x = bid & 7;
  const int k = bid >> 3;                        // 0..127
  const int brow = (((x >> 1) << 3) + (k >> 4)) << 8;
  const int bcol = (((x & 1) << 4) + (k & 15)) << 8;

  // Staging (verified involution, 64B rows): thread t covers dest row t>>2,
  // slot t&3 within an 8KB call-chunk (128 rows); source col byte:
  const int srow = t >> 2;                                   // 0..127
  const int scolb = (((t & 3) ^ ((t >> 3) & 3)) << 4);

  // Fragment ds_read offsets (within buf; add buf*32768 at use).
  int aoff[8], boff[4];
  #pragma unroll
  for (int rf = 0; rf < 8; ++rf) {
    const int ra = wm * 128 + rf * 16 + (lane & 15);
    aoff[rf] = ra * 64 + (((lane >> 4) * 16) ^ (((ra >> 1) & 3) << 4));
  }
  #pragma unroll
  for (int cf = 0; cf < 4; ++cf) {
    const int rb = wn * 64 + cf * 16 + (lane & 15);
    boff[cf] = 16384 + rb * 64 + (((lane >> 4) * 16) ^ (((rb >> 1) & 3) << 4));
  }

  const char* Ab = (const char*)Abf;
  const char* Bb = (const char*)Bbf;

  // Stage call c (0,1: A halves; 2,3: B halves) for K-tile kt into buf.
  auto stage_call = [&](int buf, int kt, int c) {
    const int h = c & 1;
    if (c < 2) {
      gload_lds16(Ab + (size_t)(brow + h * 128 + srow) * 512 + kt * 64 + scolb,
                  smem + buf * 32768 + h * 8192 + (wid << 10));
    } else {
      gload_lds16(Bb + (size_t)(bcol + h * 128 + srow) * 512 + kt * 64 + scolb,
                  smem + buf * 32768 + 16384 + h * 8192 + (wid << 10));
    }
  };

  f32x4 acc[8][4] = {};

  // ---- prologue: stage K-tile 0 ----
  #pragma unroll
  for (int c = 0; c < 4; ++c) stage_call(0, 0, c);
  asm volatile("s_waitcnt vmcnt(0)" ::: "memory");
  FULL_BARRIER();

  #pragma unroll
  for (int kt = 0; kt < NKT; ++kt) {
    const int cb = (kt & 1) * 32768;

    // B fragments for this K-tile (held across all 4 phases).
    short8 bfv[4];
    #pragma unroll
    for (int cf = 0; cf < 4; ++cf) bfv[cf] = *(const short8*)(smem + cb + boff[cf]);

    #pragma unroll
    for (int q = 0; q < 4; ++q) {
      short8 a0 = *(const short8*)(smem + cb + aoff[2 * q]);
      short8 a1 = *(const short8*)(smem + cb + aoff[2 * q + 1]);

      // Front-loaded staging for kt+1: 2 calls in q=0, 2 in q=1.
      if (kt + 1 < NKT) {
        if (q == 0) { stage_call((kt + 1) & 1, kt + 1, 0); stage_call((kt + 1) & 1, kt + 1, 1); }
        if (q == 1) { stage_call((kt + 1) & 1, kt + 1, 2); stage_call((kt + 1) & 1, kt + 1, 3); }
      }

      __builtin_amdgcn_s_setprio(1);
      #pragma unroll
      for (int cf = 0; cf < 4; ++cf) {
        acc[2 * q][cf] = __builtin_amdgcn_mfma_f32_16x16x32_bf16(
            bfv[cf], a0, acc[2 * q][cf], 0, 0, 0);
        acc[2 * q + 1][cf] = __builtin_amdgcn_mfma_f32_16x16x32_bf16(
            bfv[cf], a1, acc[2 * q + 1][cf], 0, 0, 0);
      }
      __builtin_amdgcn_s_setprio(0);
    }

    if (kt + 1 < NKT) {
      // Staged loads are >=2 phases old -> near-free drain; barrier
      // protects the buffer swap (buf is overwritten during kt+1).
      asm volatile("s_waitcnt vmcnt(0)" ::: "memory");
      FULL_BARRIER();
    }
  }

  // ---- lean epilogue: K = exp2(na + nb + 2*gamma*log2e*dot) ----
  const float c2 = 2.0f * GAMMA_F * LOG2E_F;
  f32x4 b4s[4];
  #pragma unroll
  for (int cf = 0; cf < 4; ++cf) {
    const int j0 = bcol + wn * 64 + cf * 16 + ((lane >> 4) << 2);
    b4s[cf] = *(const f32x4*)&nb[j0];
  }
  #pragma unroll
  for (int rf = 0; rf < 8; ++rf) {
    const int i = brow + wm * 128 + rf * 16 + (lane & 15);
    const float an = na[i];
    float* crow = C + (size_t)i * ND;
    #pragma unroll
    for (int cf = 0; cf < 4; ++cf) {
      const int j0 = bcol + wn * 64 + cf * 16 + ((lane >> 4) << 2);
      f32x4 arg = b4s[cf] + an;          // v_pk_add_f32 x2
      arg = acc[rf][cf] * c2 + arg;      // v_pk_fma_f32 x2
      f32x4 o;
      o[0] = fast_exp2(arg[0]);
      o[1] = fast_exp2(arg[1]);
      o[2] = fast_exp2(arg[2]);
      o[3] = fast_exp2(arg[3]);
      *(f32x4*)&crow[j0] = o;
    }
  }
}

// ---------------------------------------------------------------------------
// Fallback (tiny d_ws): 128x128 serial kernel, f32->bf16 inline.
// ---------------------------------------------------------------------------
__global__ __launch_bounds__(256) void rbf_gemm_fallback(
    const float* __restrict__ Af, const float* __restrict__ Bf,
    const float* __restrict__ na, const float* __restrict__ nb,
    float* __restrict__ C)
{
  __shared__ __align__(16) char smem[16384];
  const int t = threadIdx.x;
  const int lane = t & 63;
  const int wid = t >> 6;
  const int wm = wid >> 1, wn = wid & 1;
  const int bid = blockIdx.x;
  const int brow = (bid >> 6) << 7;
  const int bcol = (bid & 63) << 7;
  const int srow = t >> 2;
  const int scolb = (((t & 3) ^ ((t >> 3) & 3)) << 4);

  int aoff[4], boff[4];
  #pragma unroll
  for (int f = 0; f < 4; ++f) {
    const int ra = wm * 64 + f * 16 + (lane & 15);
    aoff[f] = ra * 64 + (((lane >> 4) * 16) ^ (((ra >> 1) & 3) << 4));
    const int rb = wn * 64 + f * 16 + (lane & 15);
    boff[f] = 8192 + rb * 64 + (((lane >> 4) * 16) ^ (((rb >> 1) & 3) << 4));
  }

  f32x4 acc[4][4] = {};
  for (int kt = 0; kt < 8; ++kt) {
    #pragma unroll
    for (int h = 0; h < 2; ++h) {
      const float* sa = Af + (size_t)(brow + h * 64 + srow) * KD + kt * 32 + (scolb >> 1);
      const float4 a0 = *(const float4*)sa;
      const float4 a1 = *(const float4*)(sa + 4);
      *(uint4*)(smem + h * 4096 + t * 16) = make_uint4(
          (unsigned)f2b(a0.x) | ((unsigned)f2b(a0.y) << 16),
          (unsigned)f2b(a0.z) | ((unsigned)f2b(a0.w) << 16),
          (unsigned)f2b(a1.x) | ((unsigned)f2b(a1.y) << 16),
          (unsigned)f2b(a1.z) | ((unsigned)f2b(a1.w) << 16));
      const float* sb = Bf + (size_t)(bcol + h * 64 + srow) * KD + kt * 32 + (scolb >> 1);
      const float4 b0 = *(const float4*)sb;
      const float4 b1 = *(const float4*)(sb + 4);
      *(uint4*)(smem + 8192 + h * 4096 + t * 16) = make_uint4(
          (unsigned)f2b(b0.x) | ((unsigned)f2b(b0.y) << 16),
          (unsigned)f2b(b0.z) | ((unsigned)f2b(b0.w) << 16),
          (unsigned)f2b(b1.x) | ((unsigned)f2b(b1.y) << 16),
          (unsigned)f2b(b1.z) | ((unsigned)f2b(b1.w) << 16));
    }
    __syncthreads();
    short8 af[4], bfv[4];
    #pragma unroll
    for (int f = 0; f < 4; ++f) {
      af[f]  = *(const short8*)(smem + aoff[f]);
      bfv[f] = *(const short8*)(smem + boff[f]);
    }
    #pragma unroll
    for (int fm = 0; fm < 4; ++fm)
      #pragma unroll
      for (int fn = 0; fn < 4; ++fn)
        acc[fm][fn] = __builtin_amdgcn_mfma_f32_16x16x32_bf16(
            bfv[fn], af[fm], acc[fm][fn], 0, 0, 0);
    __syncthreads();
  }

  const float c2 = 2.0f * GAMMA_F * LOG2E_F;
  #pragma unroll
  for (int fm = 0; fm < 4; ++fm) {
    const int i = brow + wm * 64 + fm * 16 + (lane & 15);
    const float an = na[i];
    float* crow = C + (size_t)i * ND;
    #pragma unroll
    for (int fn = 0; fn < 4; ++fn) {
      const int j0 = bcol + wn * 64 + fn * 16 + ((lane >> 4) << 2);
      const f32x4 b4 = *(const f32x4*)&nb[j0];
      f32x4 arg = b4 + an;
      arg = acc[fm][fn] * c2 + arg;
      f32x4 o;
      o[0] = fast_exp2(arg[0]);
      o[1] = fast_exp2(arg[1]);
      o[2] = fast_exp2(arg[2]);
      o[3] = fast_exp2(arg[3]);
      *(f32x4*)&crow[j0] = o;
    }
  }
}

// ---------------------------------------------------------------------------
extern "C" void kernel_launch(void* const* d_in, const int* in_sizes, int n_in,
                              void* d_out, int out_size, void* d_ws, size_t ws_size,
                              hipStream_t stream) {
  const float* A = (const float*)d_in[0];
  const float* B = (const float*)d_in[1];
  float* C = (float*)d_out;

  const size_t bfBytes = (size_t)ND * KD * 2;   // 4 MiB per matrix
  const size_t normBytes = (size_t)ND * 4;
  char* ws = (char*)d_ws;

  if (ws_size >= 2 * bfBytes + 2 * normBytes) {
    unsigned short* Abf = (unsigned short*)ws;
    unsigned short* Bbf = (unsigned short*)(ws + bfBytes);
    float* na = (float*)(ws + 2 * bfBytes);
    float* nb = (float*)(ws + 2 * bfBytes + normBytes);
    hipLaunchKernelGGL(norm_convert_kernel, dim3(2 * ND / 4), dim3(256), 0, stream,
                       A, B, Abf, Bbf, na, nb);
    hipLaunchKernelGGL(rbf_gemm_kernel, dim3((ND / 256) * (ND / 256)), dim3(512), 0,
                       stream, Abf, Bbf, na, nb, C);
  } else {
    float* na = (float*)ws;
    float* nb = (float*)(ws + normBytes);
    hipLaunchKernelGGL(norm_convert_kernel, dim3(2 * ND / 4), dim3(256), 0, stream,
                       A, B, (unsigned short*)nullptr, (unsigned short*)nullptr, na, nb);
    hipLaunchKernelGGL(rbf_gemm_fallback, dim3((ND / 128) * (ND / 128)), dim3(256), 0,
                       stream, A, B, na, nb, C);
  }
}